// Round 10
// baseline (749.741 us; speedup 1.0000x reference)
//
#include <hip/hip_runtime.h>

#define N_NODES 50000
#define N_EDGES 640000
#define D 128
#define D2 256
#define BN_EPS 1e-5f

typedef unsigned short ushort_t;
typedef unsigned int uint_t;

using bf16x8 = __attribute__((ext_vector_type(8))) short;
using f32x4  = __attribute__((ext_vector_type(4))) float;

__device__ inline ushort_t f2bf(float f) {
    uint_t u = __builtin_bit_cast(uint_t, f);
    u = (u + 0x7fffu + ((u >> 16) & 1u)) >> 16;   // RTNE
    return (ushort_t)u;
}
__device__ inline float bf2f(uint_t bits_lo16) {
    return __builtin_bit_cast(float, bits_lo16 << 16);
}

// ===========================================================================
// Preprocessing: CSR permutation of edges by dst (once per call).
// ===========================================================================
__global__ __launch_bounds__(256) void hist_kernel(
    const int* __restrict__ dst, int* __restrict__ hist)
{
    const int e = blockIdx.x * 256 + threadIdx.x;
    if (e < N_EDGES) atomicAdd(&hist[dst[e]], 1);
}

__global__ __launch_bounds__(256) void scan1_kernel(
    const int* __restrict__ hist, int* __restrict__ scanA,
    int* __restrict__ bsum)
{
    __shared__ int sm[256];
    const int t = threadIdx.x;
    const int idx = blockIdx.x * 256 + t;
    int val = (idx < N_NODES) ? hist[idx] : 0;
    sm[t] = val;
    __syncthreads();
#pragma unroll
    for (int off = 1; off < 256; off <<= 1) {
        const int add = (t >= off) ? sm[t - off] : 0;
        __syncthreads();
        val += add;
        sm[t] = val;
        __syncthreads();
    }
    scanA[idx] = val;
    if (t == 255) bsum[blockIdx.x] = val;
}

__global__ __launch_bounds__(256) void scan2_kernel(
    const int* __restrict__ bsum, int* __restrict__ bscan, int nb)
{
    __shared__ int sm[256];
    const int t = threadIdx.x;
    int val = (t < nb) ? bsum[t] : 0;
    sm[t] = val;
    __syncthreads();
#pragma unroll
    for (int off = 1; off < 256; off <<= 1) {
        const int add = (t >= off) ? sm[t - off] : 0;
        __syncthreads();
        val += add;
        sm[t] = val;
        __syncthreads();
    }
    bscan[t] = val;
}

__global__ __launch_bounds__(256) void scan3_kernel(
    const int* __restrict__ hist, const int* __restrict__ scanA,
    const int* __restrict__ bscan, int* __restrict__ excl)
{
    const int idx = blockIdx.x * 256 + threadIdx.x;
    if (idx < N_NODES) {
        const int carry = blockIdx.x ? bscan[blockIdx.x - 1] : 0;
        const int incl = scanA[idx] + carry;
        excl[idx] = incl - hist[idx];
        if (idx == N_NODES - 1) excl[N_NODES] = incl;
    }
}

__global__ __launch_bounds__(256) void scatter_kernel(
    const int* __restrict__ src, const int* __restrict__ dst,
    const float* __restrict__ ea, int* __restrict__ cursor,
    int* __restrict__ srcp_s, float* __restrict__ ea_s)
{
    const int e = blockIdx.x * 256 + threadIdx.x;
    if (e < N_EDGES) {
        const int t = dst[e];
        const int p = atomicAdd(&cursor[t], 1);
        srcp_s[p] = src[e];
        *(float4*)&ea_s[(size_t)p * 8]     = *(const float4*)&ea[(size_t)e * 8];
        *(float4*)&ea_s[(size_t)p * 8 + 4] = *(const float4*)&ea[(size_t)e * 8 + 4];
    }
}

// ===========================================================================
// W transpose + bf16 convert: in fp32 [L][K][Nt] -> out bf16 [L][Nt][K]
// ===========================================================================
__global__ __launch_bounds__(256) void wtrans_kernel(
    const float* __restrict__ in, ushort_t* __restrict__ out, int K, int Nt)
{
    __shared__ float tile[32][33];
    const int l = blockIdx.z;
    in  += (size_t)l * K * Nt;
    out += (size_t)l * K * Nt;
    const int n0 = blockIdx.x * 32, k0 = blockIdx.y * 32;
    const int tx = threadIdx.x & 31, ty = threadIdx.x >> 5;   // 32 x 8
#pragma unroll
    for (int i = 0; i < 32; i += 8)
        tile[ty + i][tx] = in[(size_t)(k0 + ty + i) * Nt + n0 + tx];
    __syncthreads();
#pragma unroll
    for (int i = 0; i < 32; i += 8)
        out[(size_t)(n0 + ty + i) * K + k0 + tx] = f2bf(tile[tx][ty + i]);
}

// ===========================================================================
// Aggregation (unchanged from round 8; round-7 lesson: shuffles convergent).
// ===========================================================================
__device__ __forceinline__ void msg_accum(
    const float* __restrict__ hv, const float* __restrict__ eav,
    const float (&wv)[8][8], const float* __restrict__ bev,
    float* __restrict__ acc)
{
    float m[8];
#pragma unroll
    for (int j = 0; j < 8; ++j) m[j] = bev[j];
#pragma unroll
    for (int k = 0; k < 8; ++k)
#pragma unroll
        for (int j = 0; j < 8; ++j)
            m[j] = fmaf(eav[k], wv[k][j], m[j]);
#pragma unroll
    for (int j = 0; j < 8; ++j)
        acc[j] += fmaxf(hv[j] + m[j], 0.f);
}

__device__ __forceinline__ void unpack_bn_relu(
    const uint4 v, const float* __restrict__ scv,
    const float* __restrict__ shv, float* __restrict__ hv)
{
    float f[8];
    f[0] = bf2f(v.x & 0xffffu); f[1] = bf2f(v.x >> 16);
    f[2] = bf2f(v.y & 0xffffu); f[3] = bf2f(v.y >> 16);
    f[4] = bf2f(v.z & 0xffffu); f[5] = bf2f(v.z >> 16);
    f[6] = bf2f(v.w & 0xffffu); f[7] = bf2f(v.w >> 16);
#pragma unroll
    for (int j = 0; j < 8; ++j)
        hv[j] = fmaxf(fmaf(f[j], scv[j], shv[j]), 0.f);
}

__device__ __forceinline__ void store_z(
    ushort_t* __restrict__ z, int node, int d0, float epsv,
    const float* __restrict__ hn, const float* __restrict__ acc)
{
    uint_t w[8];
#pragma unroll
    for (int j = 0; j < 8; ++j)
        w[j] = (uint_t)f2bf(fmaf(epsv, hn[j], acc[j]));
    uint4 o;
    o.x = w[0] | (w[1] << 16);
    o.y = w[2] | (w[3] << 16);
    o.z = w[4] | (w[5] << 16);
    o.w = w[6] | (w[7] << 16);
    *(uint4*)&z[(size_t)node * D + d0] = o;
}

// Layer 0: gather fp32 x rows.
__global__ __launch_bounds__(256) void agg_z_f32_kernel(
    const float* __restrict__ h, const int* __restrict__ excl,
    const int* __restrict__ srcp_s, const float* __restrict__ ea_s,
    const float* __restrict__ We_l, const float* __restrict__ be_l,
    const float* __restrict__ eps_l, ushort_t* __restrict__ z)
{
    const int lane = threadIdx.x & 63;
    const int wave = threadIdx.x >> 6;
    const int node = blockIdx.x * 4 + wave;
    const int grp  = lane >> 4;
    const int gl   = lane & 15;
    const int d0   = gl * 8;

    float wv[8][8];
#pragma unroll
    for (int k = 0; k < 8; ++k) {
        *(float4*)&wv[k][0] = *(const float4*)&We_l[k * D + d0];
        *(float4*)&wv[k][4] = *(const float4*)&We_l[k * D + d0 + 4];
    }
    float bev[8];
    *(float4*)&bev[0] = *(const float4*)&be_l[d0];
    *(float4*)&bev[4] = *(const float4*)&be_l[d0 + 4];

    const int p0 = excl[node];
    const int p1 = excl[node + 1];
    const int deg = p1 - p0;
    const int scached = (lane < deg) ? srcp_s[p0 + lane] : 0;
    const int nmain = deg < 64 ? deg : 64;

    float acc[8] = {0.f, 0.f, 0.f, 0.f, 0.f, 0.f, 0.f, 0.f};

    if (deg > 0) {
        const int niter = (nmain + 7) >> 3;
        int qA = grp, qB = grp + 4;
        float eA[8], hA[8], eB[8], hB[8];
        for (int it = 0; it < niter - 1; ++it) {
            const int sA = __shfl(scached, qA);
            const int sB = __shfl(scached, qB);
            *(float4*)&eA[0] = *(const float4*)&ea_s[(size_t)(p0 + qA) * 8];
            *(float4*)&eA[4] = *(const float4*)&ea_s[(size_t)(p0 + qA) * 8 + 4];
            *(float4*)&hA[0] = *(const float4*)&h[(size_t)sA * D + d0];
            *(float4*)&hA[4] = *(const float4*)&h[(size_t)sA * D + d0 + 4];
            *(float4*)&eB[0] = *(const float4*)&ea_s[(size_t)(p0 + qB) * 8];
            *(float4*)&eB[4] = *(const float4*)&ea_s[(size_t)(p0 + qB) * 8 + 4];
            *(float4*)&hB[0] = *(const float4*)&h[(size_t)sB * D + d0];
            *(float4*)&hB[4] = *(const float4*)&h[(size_t)sB * D + d0 + 4];
            msg_accum(hA, eA, wv, bev, acc);
            msg_accum(hB, eB, wv, bev, acc);
            qA += 8; qB += 8;
        }
        const int cA = (qA < nmain) ? qA : 0;
        const int cB = (qB < nmain) ? qB : 0;
        const int sA = __shfl(scached, cA);
        const int sB = __shfl(scached, cB);
        if (qA < nmain) {
            *(float4*)&eA[0] = *(const float4*)&ea_s[(size_t)(p0 + qA) * 8];
            *(float4*)&eA[4] = *(const float4*)&ea_s[(size_t)(p0 + qA) * 8 + 4];
            *(float4*)&hA[0] = *(const float4*)&h[(size_t)sA * D + d0];
            *(float4*)&hA[4] = *(const float4*)&h[(size_t)sA * D + d0 + 4];
            msg_accum(hA, eA, wv, bev, acc);
        }
        if (qB < nmain) {
            *(float4*)&eB[0] = *(const float4*)&ea_s[(size_t)(p0 + qB) * 8];
            *(float4*)&eB[4] = *(const float4*)&ea_s[(size_t)(p0 + qB) * 8 + 4];
            *(float4*)&hB[0] = *(const float4*)&h[(size_t)sB * D + d0];
            *(float4*)&hB[4] = *(const float4*)&h[(size_t)sB * D + d0 + 4];
            msg_accum(hB, eB, wv, bev, acc);
        }
    }
    for (int p = p0 + 64 + grp; p < p1; p += 4) {
        const int s = srcp_s[p];
        float eT[8], hT[8];
        *(float4*)&eT[0] = *(const float4*)&ea_s[(size_t)p * 8];
        *(float4*)&eT[4] = *(const float4*)&ea_s[(size_t)p * 8 + 4];
        *(float4*)&hT[0] = *(const float4*)&h[(size_t)s * D + d0];
        *(float4*)&hT[4] = *(const float4*)&h[(size_t)s * D + d0 + 4];
        msg_accum(hT, eT, wv, bev, acc);
    }

#pragma unroll
    for (int j = 0; j < 8; ++j) {
        acc[j] += __shfl_xor(acc[j], 16);
        acc[j] += __shfl_xor(acc[j], 32);
    }

    if (grp == 0) {
        float hn[8];
        *(float4*)&hn[0] = *(const float4*)&h[(size_t)node * D + d0];
        *(float4*)&hn[4] = *(const float4*)&h[(size_t)node * D + d0 + 4];
        store_z(z, node, d0, 1.0f + eps_l[0], hn, acc);
    }
}

// Layers 1,2: gather bf16 t2 rows, apply BN2+relu inline.
__global__ __launch_bounds__(256) void agg_z_bf16_kernel(
    const ushort_t* __restrict__ t2, const float* __restrict__ sc2,
    const float* __restrict__ sh2, const int* __restrict__ excl,
    const int* __restrict__ srcp_s, const float* __restrict__ ea_s,
    const float* __restrict__ We_l, const float* __restrict__ be_l,
    const float* __restrict__ eps_l, ushort_t* __restrict__ z)
{
    const int lane = threadIdx.x & 63;
    const int wave = threadIdx.x >> 6;
    const int node = blockIdx.x * 4 + wave;
    const int grp  = lane >> 4;
    const int gl   = lane & 15;
    const int d0   = gl * 8;

    float wv[8][8];
#pragma unroll
    for (int k = 0; k < 8; ++k) {
        *(float4*)&wv[k][0] = *(const float4*)&We_l[k * D + d0];
        *(float4*)&wv[k][4] = *(const float4*)&We_l[k * D + d0 + 4];
    }
    float bev[8], scv[8], shv[8];
    *(float4*)&bev[0] = *(const float4*)&be_l[d0];
    *(float4*)&bev[4] = *(const float4*)&be_l[d0 + 4];
    *(float4*)&scv[0] = *(const float4*)&sc2[d0];
    *(float4*)&scv[4] = *(const float4*)&sc2[d0 + 4];
    *(float4*)&shv[0] = *(const float4*)&sh2[d0];
    *(float4*)&shv[4] = *(const float4*)&sh2[d0 + 4];

    const int p0 = excl[node];
    const int p1 = excl[node + 1];
    const int deg = p1 - p0;
    const int scached = (lane < deg) ? srcp_s[p0 + lane] : 0;
    const int nmain = deg < 64 ? deg : 64;

    float acc[8] = {0.f, 0.f, 0.f, 0.f, 0.f, 0.f, 0.f, 0.f};

    if (deg > 0) {
        const int niter = (nmain + 7) >> 3;
        int qA = grp, qB = grp + 4;
        float eA[8], eB[8], hA[8], hB[8];
        uint4 vA, vB;
        for (int it = 0; it < niter - 1; ++it) {
            const int sA = __shfl(scached, qA);
            const int sB = __shfl(scached, qB);
            *(float4*)&eA[0] = *(const float4*)&ea_s[(size_t)(p0 + qA) * 8];
            *(float4*)&eA[4] = *(const float4*)&ea_s[(size_t)(p0 + qA) * 8 + 4];
            vA = *(const uint4*)&t2[(size_t)sA * D + d0];
            *(float4*)&eB[0] = *(const float4*)&ea_s[(size_t)(p0 + qB) * 8];
            *(float4*)&eB[4] = *(const float4*)&ea_s[(size_t)(p0 + qB) * 8 + 4];
            vB = *(const uint4*)&t2[(size_t)sB * D + d0];
            unpack_bn_relu(vA, scv, shv, hA);
            msg_accum(hA, eA, wv, bev, acc);
            unpack_bn_relu(vB, scv, shv, hB);
            msg_accum(hB, eB, wv, bev, acc);
            qA += 8; qB += 8;
        }
        const int cA = (qA < nmain) ? qA : 0;
        const int cB = (qB < nmain) ? qB : 0;
        const int sA = __shfl(scached, cA);
        const int sB = __shfl(scached, cB);
        if (qA < nmain) {
            *(float4*)&eA[0] = *(const float4*)&ea_s[(size_t)(p0 + qA) * 8];
            *(float4*)&eA[4] = *(const float4*)&ea_s[(size_t)(p0 + qA) * 8 + 4];
            vA = *(const uint4*)&t2[(size_t)sA * D + d0];
            unpack_bn_relu(vA, scv, shv, hA);
            msg_accum(hA, eA, wv, bev, acc);
        }
        if (qB < nmain) {
            *(float4*)&eB[0] = *(const float4*)&ea_s[(size_t)(p0 + qB) * 8];
            *(float4*)&eB[4] = *(const float4*)&ea_s[(size_t)(p0 + qB) * 8 + 4];
            vB = *(const uint4*)&t2[(size_t)sB * D + d0];
            unpack_bn_relu(vB, scv, shv, hB);
            msg_accum(hB, eB, wv, bev, acc);
        }
    }
    for (int p = p0 + 64 + grp; p < p1; p += 4) {
        const int s = srcp_s[p];
        float eT[8], hT[8];
        *(float4*)&eT[0] = *(const float4*)&ea_s[(size_t)p * 8];
        *(float4*)&eT[4] = *(const float4*)&ea_s[(size_t)p * 8 + 4];
        const uint4 vT = *(const uint4*)&t2[(size_t)s * D + d0];
        unpack_bn_relu(vT, scv, shv, hT);
        msg_accum(hT, eT, wv, bev, acc);
    }

#pragma unroll
    for (int j = 0; j < 8; ++j) {
        acc[j] += __shfl_xor(acc[j], 16);
        acc[j] += __shfl_xor(acc[j], 32);
    }

    if (grp == 0) {
        const uint4 vN = *(const uint4*)&t2[(size_t)node * D + d0];
        float hn[8];
        unpack_bn_relu(vN, scv, shv, hn);
        store_z(z, node, d0, 1.0f + eps_l[0], hn, acc);
    }
}

// ===========================================================================
// GEMM1, register-B streaming: t1 = z @ W1t^T + b1. N=256, K=128.
// No LDS staging, no main-loop barriers. Block = 64 rows; 4 waves x 64 cols.
// B-fragments (16 x bf16x8 = 64 VGPR) live in registers for the whole kernel;
// A-fragments load straight from global (z row-major in K -> coalesced 16B).
// ===========================================================================
__global__ __launch_bounds__(256) void gemm1_reg_kernel(
    const ushort_t* __restrict__ A, const ushort_t* __restrict__ Bt,
    const float* __restrict__ bias, ushort_t* __restrict__ out,
    float* __restrict__ gsum, float* __restrict__ gsq)
{
    __shared__ float ls_sum[D2], ls_sq[D2];
    const int tid = threadIdx.x;
    const int lane = tid & 63, wn = tid >> 6;   // wave owns cols [wn*64, wn*64+64)
    const int lr = lane & 15;
    const int lk = (lane >> 4) * 8;
    const int M0 = blockIdx.x * 64;
    ls_sum[tid] = 0.f; ls_sq[tid] = 0.f;        // tid < 256 == D2
    __syncthreads();

    bf16x8 bfr[4][4];                            // [ni][ks]
#pragma unroll
    for (int ni = 0; ni < 4; ++ni)
#pragma unroll
        for (int ks = 0; ks < 4; ++ks)
            bfr[ni][ks] = *(const bf16x8*)
                &Bt[(size_t)(wn * 64 + ni * 16 + lr) * D + ks * 32 + lk];

    const bf16x8 zfrag = {};
    f32x4 acc[4][4] = {};                        // [mi][ni]
#pragma unroll
    for (int ks = 0; ks < 4; ++ks) {
        bf16x8 af[4];
#pragma unroll
        for (int mi = 0; mi < 4; ++mi) {
            const int row = M0 + mi * 16 + lr;
            af[mi] = (row < N_NODES)
                ? *(const bf16x8*)&A[(size_t)row * D + ks * 32 + lk]
                : zfrag;
        }
#pragma unroll
        for (int mi = 0; mi < 4; ++mi)
#pragma unroll
            for (int ni = 0; ni < 4; ++ni)
                acc[mi][ni] = __builtin_amdgcn_mfma_f32_16x16x32_bf16(
                    af[mi], bfr[ni][ks], acc[mi][ni], 0, 0, 0);
    }

    // Epilogue: bias, bf16 store, per-column fp32 stats (pre-rounding).
#pragma unroll
    for (int ni = 0; ni < 4; ++ni) {
        const int cl = wn * 64 + ni * 16 + lr;
        const float bv = bias[cl];
        float ps = 0.f, pq = 0.f;
#pragma unroll
        for (int mi = 0; mi < 4; ++mi) {
            const int rbase = M0 + mi * 16 + (lane >> 4) * 4;
#pragma unroll
            for (int r = 0; r < 4; ++r) {
                const int row = rbase + r;
                if (row < N_NODES) {
                    const float v = acc[mi][ni][r] + bv;
                    out[(size_t)row * D2 + cl] = f2bf(v);
                    ps += v;
                    pq += v * v;
                }
            }
        }
        atomicAdd(&ls_sum[cl], ps);
        atomicAdd(&ls_sq[cl], pq);
    }
    __syncthreads();
    unsafeAtomicAdd(&gsum[tid], ls_sum[tid]);
    unsafeAtomicAdd(&gsq[tid], ls_sq[tid]);
}

// ===========================================================================
// GEMM2, register-B streaming, BN1+relu fused on A-load:
// t2 = relu(bn1(t1)) @ W2t^T + b2. N=128, K=256.
// 4 waves x 32 cols; B-frags 16 x bf16x8 in registers; A from global with
// f2bf(relu(fmaf(bf2f(t1),sc,sh))) -- bit-identical to staged version.
// ===========================================================================
__global__ __launch_bounds__(256) void gemm2_reg_kernel(
    const ushort_t* __restrict__ A, const float* __restrict__ sc1,
    const float* __restrict__ sh1, const ushort_t* __restrict__ Bt,
    const float* __restrict__ bias, ushort_t* __restrict__ out,
    float* __restrict__ gsum, float* __restrict__ gsq)
{
    __shared__ float ls_sum[D], ls_sq[D];
    const int tid = threadIdx.x;
    const int lane = tid & 63, wn = tid >> 6;   // wave owns cols [wn*32, wn*32+32)
    const int lr = lane & 15;
    const int lk = (lane >> 4) * 8;
    const int M0 = blockIdx.x * 64;
    if (tid < D) { ls_sum[tid] = 0.f; ls_sq[tid] = 0.f; }
    __syncthreads();

    bf16x8 bfr[2][8];                            // [ni][ks]
#pragma unroll
    for (int ni = 0; ni < 2; ++ni)
#pragma unroll
        for (int ks = 0; ks < 8; ++ks)
            bfr[ni][ks] = *(const bf16x8*)
                &Bt[(size_t)(wn * 32 + ni * 16 + lr) * D2 + ks * 32 + lk];

    f32x4 acc[4][2] = {};                        // [mi][ni]
#pragma unroll
    for (int ks = 0; ks < 8; ++ks) {
        const int kc = ks * 32 + lk;
        float scv[8], shv[8];
        *(float4*)&scv[0] = *(const float4*)&sc1[kc];
        *(float4*)&scv[4] = *(const float4*)&sc1[kc + 4];
        *(float4*)&shv[0] = *(const float4*)&sh1[kc];
        *(float4*)&shv[4] = *(const float4*)&sh1[kc + 4];
        bf16x8 af[4];
#pragma unroll
        for (int mi = 0; mi < 4; ++mi) {
            const int row = M0 + mi * 16 + lr;
            uint4 pk = make_uint4(0, 0, 0, 0);
            if (row < N_NODES) {
                const uint4 t = *(const uint4*)&A[(size_t)row * D2 + kc];
                float f[8];
                f[0] = bf2f(t.x & 0xffffu); f[1] = bf2f(t.x >> 16);
                f[2] = bf2f(t.y & 0xffffu); f[3] = bf2f(t.y >> 16);
                f[4] = bf2f(t.z & 0xffffu); f[5] = bf2f(t.z >> 16);
                f[6] = bf2f(t.w & 0xffffu); f[7] = bf2f(t.w >> 16);
#pragma unroll
                for (int j = 0; j < 8; ++j)
                    f[j] = fmaxf(fmaf(f[j], scv[j], shv[j]), 0.f);
                pk.x = (uint_t)f2bf(f[0]) | ((uint_t)f2bf(f[1]) << 16);
                pk.y = (uint_t)f2bf(f[2]) | ((uint_t)f2bf(f[3]) << 16);
                pk.z = (uint_t)f2bf(f[4]) | ((uint_t)f2bf(f[5]) << 16);
                pk.w = (uint_t)f2bf(f[6]) | ((uint_t)f2bf(f[7]) << 16);
            }
            af[mi] = __builtin_bit_cast(bf16x8, pk);
        }
#pragma unroll
        for (int mi = 0; mi < 4; ++mi)
#pragma unroll
            for (int ni = 0; ni < 2; ++ni)
                acc[mi][ni] = __builtin_amdgcn_mfma_f32_16x16x32_bf16(
                    af[mi], bfr[ni][ks], acc[mi][ni], 0, 0, 0);
    }

#pragma unroll
    for (int ni = 0; ni < 2; ++ni) {
        const int cl = wn * 32 + ni * 16 + lr;
        const float bv = bias[cl];
        float ps = 0.f, pq = 0.f;
#pragma unroll
        for (int mi = 0; mi < 4; ++mi) {
            const int rbase = M0 + mi * 16 + (lane >> 4) * 4;
#pragma unroll
            for (int r = 0; r < 4; ++r) {
                const int row = rbase + r;
                if (row < N_NODES) {
                    const float v = acc[mi][ni][r] + bv;
                    out[(size_t)row * D + cl] = f2bf(v);
                    ps += v;
                    pq += v * v;
                }
            }
        }
        atomicAdd(&ls_sum[cl], ps);
        atomicAdd(&ls_sq[cl], pq);
    }
    __syncthreads();
    if (tid < D) {
        unsafeAtomicAdd(&gsum[tid], ls_sum[tid]);
        unsafeAtomicAdd(&gsq[tid], ls_sq[tid]);
    }
}

// ---------------------------------------------------------------------------
__global__ void bnparam_kernel(const float* __restrict__ gsum,
                               const float* __restrict__ gsq,
                               const float* __restrict__ g,
                               const float* __restrict__ bt,
                               float* __restrict__ scale,
                               float* __restrict__ shift, int C)
{
    const int c = threadIdx.x;
    if (c < C) {
        const float inv_n = 1.0f / (float)N_NODES;
        const float mu = gsum[c] * inv_n;
        const float var = gsq[c] * inv_n - mu * mu;
        const float s = g[c] * rsqrtf(var + BN_EPS);
        scale[c] = s;
        shift[c] = bt[c] - mu * s;
    }
}

// ---------------------------------------------------------------------------
// Final BN2 apply (last layer only, no relu): t2 bf16 -> fp32 out
// ---------------------------------------------------------------------------
__global__ __launch_bounds__(256) void bnapply2_kernel(
    const ushort_t* __restrict__ t, const float* __restrict__ sc,
    const float* __restrict__ sh, float* __restrict__ outp)
{
    const size_t idx = (size_t)blockIdx.x * 256 + threadIdx.x;  // 8-elem idx
    const int c = (int)(idx & 15) * 8;
    const uint4 v = ((const uint4*)t)[idx];
    const float4 s0 = *(const float4*)&sc[c];
    const float4 s1 = *(const float4*)&sc[c + 4];
    const float4 h0 = *(const float4*)&sh[c];
    const float4 h1 = *(const float4*)&sh[c + 4];
    float4 r0, r1;
    r0.x = fmaf(bf2f(v.x & 0xffffu), s0.x, h0.x);
    r0.y = fmaf(bf2f(v.x >> 16),     s0.y, h0.y);
    r0.z = fmaf(bf2f(v.y & 0xffffu), s0.z, h0.z);
    r0.w = fmaf(bf2f(v.y >> 16),     s0.w, h0.w);
    r1.x = fmaf(bf2f(v.z & 0xffffu), s1.x, h1.x);
    r1.y = fmaf(bf2f(v.z >> 16),     s1.y, h1.y);
    r1.z = fmaf(bf2f(v.w & 0xffffu), s1.z, h1.z);
    r1.w = fmaf(bf2f(v.w >> 16),     s1.w, h1.w);
    *(float4*)&outp[idx * 8]     = r0;
    *(float4*)&outp[idx * 8 + 4] = r1;
}

// ---------------------------------------------------------------------------
extern "C" void kernel_launch(void* const* d_in, const int* in_sizes, int n_in,
                              void* d_out, int out_size, void* d_ws, size_t ws_size,
                              hipStream_t stream)
{
    const float* x         = (const float*)d_in[0];
    const int*   edge_index= (const int*)d_in[1];
    const float* edge_attr = (const float*)d_in[2];
    const float* eps       = (const float*)d_in[3];
    const float* We        = (const float*)d_in[4];
    const float* be        = (const float*)d_in[5];
    const float* W1        = (const float*)d_in[6];
    const float* b1        = (const float*)d_in[7];
    const float* g1        = (const float*)d_in[8];
    const float* bt1       = (const float*)d_in[9];
    const float* W2        = (const float*)d_in[10];
    const float* b2        = (const float*)d_in[11];
    const float* gbn       = (const float*)d_in[12];
    const float* bbn       = (const float*)d_in[13];
    float* out = (float*)d_out;

    float* ws = (float*)d_ws;
    const size_t ND = (size_t)N_NODES * D;        // 6.4M
    float* EAS  = ws;                              // 5,120,000 floats
    float* ZB   = EAS + (size_t)N_EDGES * 8;       // ND bf16 = ND/2 floats
    float* T2B  = ZB + ND / 2;                     // ND bf16
    float* T1B  = T2B + ND / 2;                    // N*256 bf16 = ND floats
    float* STATS = T1B + ND;
    float* gsum1 = STATS;               // 3*256
    float* gsq1  = gsum1 + 3 * 256;
    float* gsum2 = gsq1 + 3 * 256;      // 3*128
    float* gsq2  = gsum2 + 3 * 128;
    float* scale1 = gsq2 + 3 * 128;     // 256
    float* shift1 = scale1 + 256;
    float* sc2buf = shift1 + 256;       // 3*128 (per-layer BN2 scale)
    float* sh2buf = sc2buf + 3 * 128;   // 3*128

    ushort_t* zbuf  = (ushort_t*)ZB;
    ushort_t* t2buf = (ushort_t*)T2B;
    ushort_t* t1buf = (ushort_t*)T1B;

    // Transient sort scratch aliased into t1buf region (dead before gemm1 l0)
    int* hist   = (int*)T1B;
    int* scanA  = hist + N_NODES;
    int* bsum   = scanA + 50176;
    int* bscan  = bsum + 256;
    int* cursor = bscan + 256;

    // Persistent CSR + bf16 weights in d_out (overwritten by final bnapply2)
    int* srcp_s = (int*)d_out;                    // 640000
    int* excl   = srcp_s + N_EDGES;               // 50001
    ushort_t* W1t = (ushort_t*)((int*)d_out + 690008);  // [3][256][128]
    ushort_t* W2t = W1t + 3 * D2 * D;                    // [3][128][256]

    const int* srcp = edge_index;
    const int* dstp = edge_index + N_EDGES;

    hipMemsetAsync(STATS, 0, 2304 * sizeof(float), stream);
    hipMemsetAsync(hist, 0, N_NODES * sizeof(int), stream);

    const int EB = (N_EDGES + 255) / 256;
    const int NB = (N_NODES + 255) / 256;
    hist_kernel<<<EB, 256, 0, stream>>>(dstp, hist);
    scan1_kernel<<<NB, 256, 0, stream>>>(hist, scanA, bsum);
    scan2_kernel<<<1, 256, 0, stream>>>(bsum, bscan, NB);
    scan3_kernel<<<NB, 256, 0, stream>>>(hist, scanA, bscan, excl);
    hipMemcpyAsync(cursor, excl, N_NODES * sizeof(int),
                   hipMemcpyDeviceToDevice, stream);
    scatter_kernel<<<EB, 256, 0, stream>>>(srcp, dstp, edge_attr,
                                           cursor, srcp_s, EAS);

    wtrans_kernel<<<dim3(8, 4, 3), 256, 0, stream>>>(W1, W1t, D, D2);
    wtrans_kernel<<<dim3(4, 8, 3), 256, 0, stream>>>(W2, W2t, D2, D);

    const int MG = (N_NODES + 63) / 64;   // 782

    for (int l = 0; l < 3; ++l) {
        if (l == 0) {
            agg_z_f32_kernel<<<N_NODES / 4, 256, 0, stream>>>(
                x, excl, srcp_s, EAS,
                We + (size_t)l * 8 * D, be + (size_t)l * D, eps + l, zbuf);
        } else {
            agg_z_bf16_kernel<<<N_NODES / 4, 256, 0, stream>>>(
                t2buf, sc2buf + (l - 1) * 128, sh2buf + (l - 1) * 128,
                excl, srcp_s, EAS,
                We + (size_t)l * 8 * D, be + (size_t)l * D, eps + l, zbuf);
        }

        gemm1_reg_kernel<<<MG, 256, 0, stream>>>(
            zbuf, W1t + (size_t)l * D2 * D, b1 + (size_t)l * D2,
            t1buf, gsum1 + l * 256, gsq1 + l * 256);

        bnparam_kernel<<<1, 256, 0, stream>>>(
            gsum1 + l * 256, gsq1 + l * 256,
            g1 + (size_t)l * D2, bt1 + (size_t)l * D2, scale1, shift1, D2);

        gemm2_reg_kernel<<<MG, 256, 0, stream>>>(
            t1buf, scale1, shift1,
            W2t + (size_t)l * D * D2, b2 + (size_t)l * D, t2buf,
            gsum2 + l * 128, gsq2 + l * 128);

        bnparam_kernel<<<1, 256, 0, stream>>>(
            gsum2 + l * 128, gsq2 + l * 128,
            gbn + (size_t)l * D, bbn + (size_t)l * D,
            sc2buf + l * 128, sh2buf + l * 128, D);
    }

    bnapply2_kernel<<<(N_NODES * D / 8) / 256, 256, 0, stream>>>(
        t2buf, sc2buf + 2 * 128, sh2buf + 2 * 128, out);
}